// Round 1
// 356.163 us; speedup vs baseline: 1.0367x; 1.0367x over previous
//
#include <hip/hip_runtime.h>
#include <math.h>

// GIN v7: 4-stream software-pipelined gather in agg_kernel.
// v6.1 gather was latency-serial per node (LDS idx -> addr -> random global
// load -> accumulate ~800cy, 8 loads in flight). Now 4 independent node
// streams per wave issue 32 gather loads + 4 self prefetches in flight;
// finalized rows are written straight to H1 (runtime node idx -> LDS, not
// a runtime-indexed reg array). H1/H2 swapped in scratch so H1 no longer
// aliases lcol (H2/w1nh alias lcol's region instead; first write to it is
// after the post-gather __syncthreads when lcol is dead block-wide).

#define NNODES 100000
#define NEDGES 1600000
#define NGRAPHS 512
#define NB 782
#define NBH 1564
#define BCAP 2560
#define LCAP 2304
#define GOFS 72
#define CHUNK 4096
#define NCHUNKS 391
#define HSTR 72   // H1/H2 row stride (u16): 144B, 36 dwords = 4 mod 32
#define XSTR 136  // gemm x-tile row stride (u16)

typedef unsigned short u16;
typedef unsigned int u32;
typedef __attribute__((ext_vector_type(8))) short short8;
typedef __attribute__((ext_vector_type(4))) float f32x4;

__device__ __forceinline__ u16 f2b(float f) {
  union { float f; unsigned u; } v;
  v.f = f;
  unsigned r = v.u + 0x7FFF + ((v.u >> 16) & 1);
  return (u16)(r >> 16);
}
__device__ __forceinline__ float b2f(u16 h) {
  union { unsigned u; float f; } v;
  v.u = ((unsigned)h) << 16;
  return v.f;
}
#define LDS_FENCE() __asm__ volatile("s_waitcnt lgkmcnt(0)" ::: "memory")

// ---------------- init ----------------

__global__ __launch_bounds__(256) void init_kernel(int* __restrict__ gcur,
                                                   u16* __restrict__ zA,
                                                   u16* __restrict__ zB) {
  int i = blockIdx.x * 256 + threadIdx.x;
  if (i < NB) gcur[i] = i * BCAP;
  if (blockIdx.x == 3) {
    int t = threadIdx.x;
    if (t < 64) zA[(size_t)NNODES * 64 + t] = 0;
    else if (t < 128) zB[(size_t)NNODES * 64 + (t - 64)] = 0;
  }
}

// ---------------- per-graph node counts (binary search, batch sorted) -----

__device__ __forceinline__ int lb_dev(const int* __restrict__ a, int n, int v) {
  int lo = 0, hi = n;
  while (lo < hi) {
    int m = (lo + hi) >> 1;
    if (a[m] < v)
      lo = m + 1;
    else
      hi = m;
  }
  return lo;
}

__global__ __launch_bounds__(256) void cnt_kernel(const int* __restrict__ batch,
                                                  int* __restrict__ gcnt) {
  int g = blockIdx.x * 256 + threadIdx.x;
  if (g < NGRAPHS)
    gcnt[g] = lb_dev(batch, NNODES, g + 1) - lb_dev(batch, NNODES, g);
}

// ---------------- weight pre-swizzle to MFMA B-fragment order -------------

__global__ __launch_bounds__(256) void prep_kernel(
    const float* __restrict__ w1g, const float* __restrict__ w2a,
    const float* __restrict__ w2b, const float* __restrict__ w2c,
    const float* __restrict__ w1b, const float* __restrict__ w1c,
    u16* __restrict__ w1f, u16* __restrict__ w2fa, u16* __restrict__ w2fb,
    u16* __restrict__ w2fc, u16* __restrict__ w1nfb, u16* __restrict__ w1nfc) {
  int blk = blockIdx.x, tid = threadIdx.x;
  if (blk == 0) {  // 128x64
    for (int i = tid; i < 8192; i += 256) {
      int jj = i & 7, lane = (i >> 3) & 63, c = i >> 9;
      int nt = c >> 2, ks = c & 3;
      int mrow = lane & 15, quad = lane >> 4;
      w1f[i] = f2b(w1g[(ks * 32 + quad * 8 + jj) * 64 + nt * 16 + mrow]);
    }
  } else {  // 64x64
    const float* s = (blk == 1) ? w2a : (blk == 2) ? w2b : (blk == 3) ? w2c
                    : (blk == 4) ? w1b : w1c;
    u16* d = (blk == 1) ? w2fa : (blk == 2) ? w2fb : (blk == 3) ? w2fc
             : (blk == 4) ? w1nfb : w1nfc;
    for (int i = tid; i < 4096; i += 256) {
      int jj = i & 7, lane = (i >> 3) & 63, c = i >> 9;
      int nt = c >> 1, ks = c & 1;
      int mrow = lane & 15, quad = lane >> 4;
      d[i] = f2b(s[(ks * 32 + quad * 8 + jj) * 64 + nt * 16 + mrow]);
    }
  }
}

// ---------------- binned scatter ----------------

__global__ __launch_bounds__(512) void bin_kernel(const int* __restrict__ src,
                                                  const int* __restrict__ dst,
                                                  int* __restrict__ gcur,
                                                  int* __restrict__ st) {
  __shared__ int hist[NB];
  __shared__ int lofs[NB + 1];
  __shared__ int lcur[NB];
  __shared__ int gbase[NB];
  __shared__ int sd[1024];
  __shared__ int staged[CHUNK];
  __shared__ u16 stb[CHUNK];
  const int t = threadIdx.x;
  const int e0 = blockIdx.x * CHUNK;
  const int n = min(CHUNK, NEDGES - e0);

  for (int i = t; i < NB; i += 512) hist[i] = 0;
  __syncthreads();

  int pk[8];
  int bk[8];
#pragma unroll
  for (int k = 0; k < 8; ++k) {
    int i = t + k * 512;
    if (i < n) {
      int s = src[e0 + i];
      int d = dst[e0 + i];
      int b = d >> 7;
      pk[k] = (s << 7) | (d & 127);
      bk[k] = b;
      atomicAdd(&hist[b], 1);
    } else {
      bk[k] = -1;
    }
  }
  __syncthreads();

  sd[t] = (t < NB) ? hist[t] : 0;
  sd[t + 512] = (t + 512 < NB) ? hist[t + 512] : 0;
  __syncthreads();
  for (int off = 1; off < 1024; off <<= 1) {
    int v0 = (t >= off) ? sd[t - off] : 0;
    int v1 = (t + 512 >= off) ? sd[t + 512 - off] : 0;
    __syncthreads();
    sd[t] += v0;
    sd[t + 512] += v1;
    __syncthreads();
  }
  if (t == 0) lofs[0] = 0;
  for (int i = t; i < NB; i += 512) {
    int inc = sd[i];
    int c = hist[i];
    lofs[i + 1] = inc;
    lcur[i] = inc - c;
    gbase[i] = c ? atomicAdd(&gcur[i], c) : 0;
  }
  __syncthreads();

#pragma unroll
  for (int k = 0; k < 8; ++k) {
    if (bk[k] >= 0) {
      int r = atomicAdd(&lcur[bk[k]], 1);
      staged[r] = pk[k];
      stb[r] = (u16)bk[k];
    }
  }
  __syncthreads();

  for (int i = t; i < n; i += 512) {
    int b = stb[i];
    st[gbase[b] + (i - lofs[b])] = staged[i];
  }
}

// ---------------- CSR build (once) ----------------

__global__ __launch_bounds__(256) void csr_kernel(const int* __restrict__ gcur,
                                                  const int* __restrict__ st,
                                                  int* __restrict__ glofs,
                                                  int* __restrict__ glcol) {
  __shared__ int lcol[LCAP];
  __shared__ int lhist[64];
  __shared__ int lofs[65];
  __shared__ int lcur[64];
  __shared__ int ssc[64];
  const int tid = threadIdx.x;
  const int blk = blockIdx.x;
  const int bkt = blk >> 1;
  const int half = blk & 1;
  const int ofs = bkt * BCAP;
  const int cnt = min(gcur[bkt] - ofs, BCAP);

  if (tid < 64) lhist[tid] = 0;
  __syncthreads();
  for (int i = tid; i < cnt; i += 256) {
    int d7 = st[ofs + i] & 127;
    if ((d7 >> 6) == half) atomicAdd(&lhist[d7 & 63], 1);
  }
  __syncthreads();
  if (tid < 64) ssc[tid] = (lhist[tid] + 15) & ~15;
  __syncthreads();
  for (int off = 1; off < 64; off <<= 1) {
    int v = (tid < 64 && tid >= off) ? ssc[tid - off] : 0;
    __syncthreads();
    if (tid < 64) ssc[tid] += v;
    __syncthreads();
  }
  if (tid < 64) {
    lofs[tid + 1] = ssc[tid];
    lcur[tid] = ssc[tid] - ((lhist[tid] + 15) & ~15);
  }
  if (tid == 0) lofs[0] = 0;
  __syncthreads();
  for (int i = tid; i < cnt; i += 256) {
    int p = st[ofs + i];
    int d7 = p & 127;
    if ((d7 >> 6) == half) {
      int r = atomicAdd(&lcur[d7 & 63], 1);
      if (r < LCAP) lcol[r] = p >> 7;
    }
  }
  __syncthreads();
  if (tid < 64) {
    int re = min(lofs[tid + 1], LCAP);
    for (int r = lcur[tid]; r < re; ++r) lcol[r] = NNODES;
  }
  __syncthreads();
  if (tid < 65) glofs[blk * GOFS + tid] = min(lofs[tid], LCAP);
  int L = min(lofs[64], LCAP);
  int4* gdst = (int4*)(glcol + (size_t)blk * LCAP);
  const int4* lsrc = (const int4*)lcol;
  for (int i = tid; i < (L >> 2); i += 256) gdst[i] = lsrc[i];
}

// ---------------- GEMM (MFMA): z = x(Nx128) @ w1, z bf16 ----------------

__global__ __launch_bounds__(256) void gemm128_kernel(
    const float* __restrict__ x, const u16* __restrict__ w1f,
    u16* __restrict__ z) {
  __shared__ u16 w1h[128 * 64];  // fragment order, 16 KB
  __shared__ u16 Xt[64 * XSTR];  // 17 KB; reused as z-tile
  const int tid = threadIdx.x;
  const int base = blockIdx.x * 64;
  for (int i = tid; i < 1024; i += 256) ((int4*)w1h)[i] = ((const int4*)w1f)[i];
  for (int i = tid; i < 2048; i += 256) {
    int n = i >> 5, c4 = i & 31;
    int nn = base + n;
    float4 v = make_float4(0.f, 0.f, 0.f, 0.f);
    if (nn < NNODES) v = *(const float4*)&x[(size_t)nn * 128 + 4 * c4];
    u32 p0 = (u32)f2b(v.x) | ((u32)f2b(v.y) << 16);
    u32 p1 = (u32)f2b(v.z) | ((u32)f2b(v.w) << 16);
    *(u32*)&Xt[n * XSTR + 4 * c4] = p0;
    *(u32*)&Xt[n * XSTR + 4 * c4 + 2] = p1;
  }
  __syncthreads();
  const int lane = tid & 63;
  const int wv = tid >> 6;
  const int mrow = lane & 15;
  const int quad = lane >> 4;
  f32x4 accs[4];
#pragma unroll
  for (int nt = 0; nt < 4; ++nt) {
    f32x4 acc = {0.f, 0.f, 0.f, 0.f};
#pragma unroll
    for (int ks = 0; ks < 4; ++ks) {
      short8 afr = *(const short8*)&Xt[(wv * 16 + mrow) * XSTR + ks * 32 + quad * 8];
      short8 bfr = *(const short8*)&w1h[((nt * 4 + ks) * 64 + lane) * 8];
      acc = __builtin_amdgcn_mfma_f32_16x16x32_bf16(afr, bfr, acc, 0, 0, 0);
    }
    accs[nt] = acc;
  }
  __syncthreads();
  u16* Zt = Xt;
#pragma unroll
  for (int nt = 0; nt < 4; ++nt)
#pragma unroll
    for (int r = 0; r < 4; ++r)
      Zt[(wv * 16 + quad * 4 + r) * HSTR + nt * 16 + mrow] = f2b(accs[nt][r]);
  __syncthreads();
  for (int i = tid; i < 2048; i += 256) {
    int n = i >> 5, kk = i & 31;
    int nn = base + n;
    if (nn < NNODES) *(u32*)&z[(size_t)nn * 64 + 2 * kk] = *(u32*)&Zt[n * HSTR + 2 * kk];
  }
}

// ---------------- agg v7: 4-stream pipelined gather + MFMA MLP ------------

#define GIN_SETUP(S)                                         \
  {                                                          \
    int ln_ = n0 + j##S;                                     \
    int nn_ = base + ln_;                                    \
    int sn_ = (nn_ < NNODES) ? nn_ : NNODES;                 \
    e##S = lofs[ln_];                                        \
    re##S = lofs[ln_ + 1];                                   \
    self##S = zin[(size_t)sn_ * 64 + f];                     \
    pa0##S = 0.f;                                            \
    pa1##S = 0.f;                                            \
    pb0##S = 0.f;                                            \
    pb1##S = 0.f;                                            \
  }

#define GIN_ISSUE(S)                                         \
  if (act##S) {                                              \
    pend##S = (e##S < re##S);                                \
    if (pend##S) {                                           \
      int c0_ = lcol[e##S + 0 + sub];                        \
      int c1_ = lcol[e##S + 2 + sub];                        \
      int c2_ = lcol[e##S + 4 + sub];                        \
      int c3_ = lcol[e##S + 6 + sub];                        \
      int c4_ = lcol[e##S + 8 + sub];                        \
      int c5_ = lcol[e##S + 10 + sub];                       \
      int c6_ = lcol[e##S + 12 + sub];                       \
      int c7_ = lcol[e##S + 14 + sub];                       \
      v0##S = *(const u32*)&zin[(size_t)c0_ * 64 + 2 * fl];  \
      v1##S = *(const u32*)&zin[(size_t)c1_ * 64 + 2 * fl];  \
      v2##S = *(const u32*)&zin[(size_t)c2_ * 64 + 2 * fl];  \
      v3##S = *(const u32*)&zin[(size_t)c3_ * 64 + 2 * fl];  \
      v4##S = *(const u32*)&zin[(size_t)c4_ * 64 + 2 * fl];  \
      v5##S = *(const u32*)&zin[(size_t)c5_ * 64 + 2 * fl];  \
      v6##S = *(const u32*)&zin[(size_t)c6_ * 64 + 2 * fl];  \
      v7##S = *(const u32*)&zin[(size_t)c7_ * 64 + 2 * fl];  \
    }                                                        \
  }

#define GIN_ACCUM(S)                                         \
  if (act##S) {                                              \
    if (pend##S) {                                           \
      pa0##S += __uint_as_float(v0##S << 16);                \
      pb0##S += __uint_as_float(v0##S & 0xffff0000u);        \
      pa1##S += __uint_as_float(v1##S << 16);                \
      pb1##S += __uint_as_float(v1##S & 0xffff0000u);        \
      pa0##S += __uint_as_float(v2##S << 16);                \
      pb0##S += __uint_as_float(v2##S & 0xffff0000u);        \
      pa1##S += __uint_as_float(v3##S << 16);                \
      pb1##S += __uint_as_float(v3##S & 0xffff0000u);        \
      pa0##S += __uint_as_float(v4##S << 16);                \
      pb0##S += __uint_as_float(v4##S & 0xffff0000u);        \
      pa1##S += __uint_as_float(v5##S << 16);                \
      pb1##S += __uint_as_float(v5##S & 0xffff0000u);        \
      pa0##S += __uint_as_float(v6##S << 16);                \
      pb0##S += __uint_as_float(v6##S & 0xffff0000u);        \
      pa1##S += __uint_as_float(v7##S << 16);                \
      pb1##S += __uint_as_float(v7##S & 0xffff0000u);        \
      e##S += 16;                                            \
    }                                                        \
    if (e##S >= re##S) {                                     \
      float sa_ = pa0##S + pa1##S;                           \
      float sb_ = pb0##S + pb1##S;                           \
      sa_ += __shfl_xor(sa_, 32);                            \
      sb_ += __shfl_xor(sb_, 32);                            \
      float sum_ = sub ? sb_ : sa_;                          \
      float h_ = fmaxf(sum_ + e1 * b2f(self##S) + b1v, 0.f); \
      H1[(n0 + j##S) * HSTR + f] = f2b(h_);                  \
      j##S += 4;                                             \
      if (j##S < 16)                                         \
        GIN_SETUP(S)                                         \
      else                                                   \
        act##S = false;                                      \
    }                                                        \
  }

template <bool HAS_NEXT>
__global__ __launch_bounds__(256) void agg_kernel(
    const u16* __restrict__ zin, const float* __restrict__ b1,
    const u16* __restrict__ w2f, const float* __restrict__ b2,
    const u16* __restrict__ w1nf, const float* __restrict__ eps, int li,
    const int* __restrict__ glofs, const int* __restrict__ glcol,
    const int* __restrict__ batch, float* __restrict__ gsum,
    float* __restrict__ gmax, u16* __restrict__ zn) {
  __shared__ u16 w2h[64 * 64];  // fragment order, 8 KB
  __shared__ float b2s[64];
  __shared__ int lofs[65];
  __shared__ int bt[64];
  __shared__ __align__(16) char scratch[2 * 64 * HSTR * 2];  // 18432 B
  int* lcol = (int*)scratch;                   // 9216 B, dead after gather
  u16* H2 = (u16*)scratch;                     // first region (post-gather)
  u16* H1 = (u16*)(scratch + 64 * HSTR * 2);   // second region (gather-live)
  u16* w1nh = (u16*)(scratch + 64 * HSTR * 2); // aliases H1 after matmul1
  const int tid = threadIdx.x;
  const int lane = tid & 63;
  const int wv = tid >> 6;
  const int sub = lane >> 5;
  const int fl = lane & 31;
  const int f = 2 * fl + sub;
  const int blk = blockIdx.x;
  const int base = ((blk >> 1) << 7) + ((blk & 1) << 6);

  for (int i = tid; i < 512; i += 256) ((int4*)w2h)[i] = ((const int4*)w2f)[i];
  if (tid < 64) {
    b2s[tid] = b2[tid];
    int nn = base + tid;
    bt[tid] = (nn < NNODES) ? batch[nn] : -1;
  }
  if (tid < 65) lofs[tid] = glofs[blk * GOFS + tid];
  __syncthreads();
  const int L = lofs[64];
  {
    int4* ldst = (int4*)lcol;
    const int4* gsrc = (const int4*)(glcol + (size_t)blk * LCAP);
    for (int i = tid; i < (L >> 2); i += 256) ldst[i] = gsrc[i];
  }
  __syncthreads();

  const float e1 = 1.0f + eps[li];
  const float b1v = b1[f];
  const int n0 = wv * 16;

  // ---- 4-stream gather: 32 gather loads + 4 self loads in flight ----
  int jA = 0, jB = 1, jC = 2, jD = 3;
  int eA = 0, eB = 0, eC = 0, eD = 0;
  int reA = 0, reB = 0, reC = 0, reD = 0;
  bool actA = true, actB = true, actC = true, actD = true;
  bool pendA = false, pendB = false, pendC = false, pendD = false;
  u16 selfA = 0, selfB = 0, selfC = 0, selfD = 0;
  float pa0A, pa1A, pb0A, pb1A, pa0B, pa1B, pb0B, pb1B;
  float pa0C, pa1C, pb0C, pb1C, pa0D, pa1D, pb0D, pb1D;
  u32 v0A = 0, v1A = 0, v2A = 0, v3A = 0, v4A = 0, v5A = 0, v6A = 0, v7A = 0;
  u32 v0B = 0, v1B = 0, v2B = 0, v3B = 0, v4B = 0, v5B = 0, v6B = 0, v7B = 0;
  u32 v0C = 0, v1C = 0, v2C = 0, v3C = 0, v4C = 0, v5C = 0, v6C = 0, v7C = 0;
  u32 v0D = 0, v1D = 0, v2D = 0, v3D = 0, v4D = 0, v5D = 0, v6D = 0, v7D = 0;
  GIN_SETUP(A)
  GIN_SETUP(B)
  GIN_SETUP(C)
  GIN_SETUP(D)
  while (actA || actB || actC || actD) {
    GIN_ISSUE(A)
    GIN_ISSUE(B)
    GIN_ISSUE(C)
    GIN_ISSUE(D)
    GIN_ACCUM(A)
    GIN_ACCUM(B)
    GIN_ACCUM(C)
    GIN_ACCUM(D)
  }
  __syncthreads();  // all lcol reads done block-wide; H1 fully written

  const int mrow = lane & 15;
  const int quad = lane >> 4;
  // matmul1: H2 = relu(H1 @ w2 + b2)  (A rows = own wave quarter)
  f32x4 m1[4];
#pragma unroll
  for (int nt = 0; nt < 4; ++nt) {
    f32x4 acc = {0.f, 0.f, 0.f, 0.f};
#pragma unroll
    for (int ks = 0; ks < 2; ++ks) {
      short8 afr = *(const short8*)&H1[(wv * 16 + mrow) * HSTR + ks * 32 + quad * 8];
      short8 bfr = *(const short8*)&w2h[((nt * 2 + ks) * 64 + lane) * 8];
      acc = __builtin_amdgcn_mfma_f32_16x16x32_bf16(afr, bfr, acc, 0, 0, 0);
    }
    m1[nt] = acc;
  }
  LDS_FENCE();
#pragma unroll
  for (int nt = 0; nt < 4; ++nt) {
    float bb = b2s[nt * 16 + mrow];
#pragma unroll
    for (int r = 0; r < 4; ++r)
      H2[(wv * 16 + quad * 4 + r) * HSTR + nt * 16 + mrow] =
          f2b(fmaxf(m1[nt][r] + bb, 0.f));
  }
  LDS_FENCE();

  // fused pooling: own-wave quarter of H2 (rows n0..n0+15), lane = feature
  {
    float s = 0.f, m = 0.f;
    int cur = bt[n0];
#pragma unroll 1
    for (int j = 0; j < 16; ++j) {
      int b = bt[n0 + j];
      if (b != cur) {
        if (cur >= 0) {
          atomicAdd(&gsum[cur * 192 + li * 64 + lane], s);
          atomicMax((u32*)&gmax[cur * 192 + li * 64 + lane], __float_as_uint(m));
        }
        s = 0.f;
        m = 0.f;
        cur = b;
      }
      if (b >= 0) {
        float v = b2f(H2[(n0 + j) * HSTR + lane]);
        s += v;
        m = fmaxf(m, v);
      }
    }
    if (cur >= 0) {
      atomicAdd(&gsum[cur * 192 + li * 64 + lane], s);
      atomicMax((u32*)&gmax[cur * 192 + li * 64 + lane], __float_as_uint(m));
    }
  }

  if (HAS_NEXT) {
    __syncthreads();  // H1 fully dead everywhere; H2 fully written
    for (int i = tid; i < 512; i += 256)
      ((int4*)w1nh)[i] = ((const int4*)w1nf)[i];
    __syncthreads();
    // matmul2: zn = H2 @ w1n (A rows = own quarter); results to regs first
    f32x4 m2[4];
#pragma unroll
    for (int nt = 0; nt < 4; ++nt) {
      f32x4 acc = {0.f, 0.f, 0.f, 0.f};
#pragma unroll
      for (int ks = 0; ks < 2; ++ks) {
        short8 afr = *(const short8*)&H2[(wv * 16 + mrow) * HSTR + ks * 32 + quad * 8];
        short8 bfr = *(const short8*)&w1nh[((nt * 2 + ks) * 64 + lane) * 8];
        acc = __builtin_amdgcn_mfma_f32_16x16x32_bf16(afr, bfr, acc, 0, 0, 0);
      }
      m2[nt] = acc;
    }
    LDS_FENCE();  // all A-reads of own H2 rows done before overwrite
#pragma unroll
    for (int nt = 0; nt < 4; ++nt)
#pragma unroll
      for (int r = 0; r < 4; ++r)
        H2[(wv * 16 + quad * 4 + r) * HSTR + nt * 16 + mrow] = f2b(m2[nt][r]);
    __syncthreads();
    for (int i = tid; i < 2048; i += 256) {
      int n = i >> 5, kk = i & 31;
      int nn = base + n;
      if (nn < NNODES)
        *(u32*)&zn[(size_t)nn * 64 + 2 * kk] = *(u32*)&H2[n * HSTR + 2 * kk];
    }
  }
}

// ---------------- Head: pooled stats -> fc1 -> fc2 -> sigmoid -------------

__global__ __launch_bounds__(256) void head_kernel(
    const float* __restrict__ gsum, const float* __restrict__ gmax,
    const int* __restrict__ gcnt, const float* __restrict__ fc1w,
    const float* __restrict__ fc1b, const float* __restrict__ fc2w,
    const float* __restrict__ fc2b, float* __restrict__ out) {
  __shared__ float gs[4 * 576];
  int tid = threadIdx.x;
  int g0 = blockIdx.x * 4;
  for (int i = tid; i < 4 * 192; i += 256) {
    int w = i / 192, idx = i - w * 192;
    int gi = g0 + w;
    float S = gsum[gi * 192 + idx];
    float M = gmax[gi * 192 + idx];
    float C = (float)gcnt[gi];
    gs[w * 576 + idx] = S / fmaxf(C, 1.0f);
    gs[w * 576 + 192 + idx] = M;
    gs[w * 576 + 384 + idx] = S;
  }
  __syncthreads();
  int wv = tid >> 6, lane = tid & 63;
  int gi = g0 + wv;
  const float* grow = &gs[wv * 576];
  float acc = fc1b[lane];
#pragma unroll 8
  for (int k = 0; k < 576; ++k) acc += grow[k] * fc1w[k * 64 + lane];
  acc = fmaxf(acc, 0.f);
  float p0 = acc * fc2w[lane * 2 + 0];
  float p1 = acc * fc2w[lane * 2 + 1];
  for (int off = 32; off; off >>= 1) {
    p0 += __shfl_down(p0, off);
    p1 += __shfl_down(p1, off);
  }
  if (lane == 0) {
    out[gi * 2 + 0] = 1.f / (1.f + __expf(-(p0 + fc2b[0])));
    out[gi * 2 + 1] = 1.f / (1.f + __expf(-(p1 + fc2b[1])));
  }
}

// ---------------- launch ----------------

extern "C" void kernel_launch(void* const* d_in, const int* in_sizes, int n_in,
                              void* d_out, int out_size, void* d_ws,
                              size_t ws_size, hipStream_t stream) {
  const float* x = (const float*)d_in[0];
  const int* ei = (const int*)d_in[1];
  const int* src = ei;
  const int* dst = ei + NEDGES;
  const int* batch = (const int*)d_in[2];
  const float* lw1[3] = {(const float*)d_in[3], (const float*)d_in[7],
                         (const float*)d_in[11]};
  const float* lb1[3] = {(const float*)d_in[4], (const float*)d_in[8],
                         (const float*)d_in[12]};
  const float* lw2[3] = {(const float*)d_in[5], (const float*)d_in[9],
                         (const float*)d_in[13]};
  const float* lb2[3] = {(const float*)d_in[6], (const float*)d_in[10],
                         (const float*)d_in[14]};
  const float* eps = (const float*)d_in[15];
  const float* fc1w = (const float*)d_in[16];
  const float* fc1b = (const float*)d_in[17];
  const float* fc2w = (const float*)d_in[18];
  const float* fc2b = (const float*)d_in[19];
  float* out = (float*)d_out;

  char* p = (char*)d_ws;
  auto carve = [&](size_t bytes) {
    void* r = (void*)p;
    p += (bytes + 1023) & ~(size_t)1023;
    return r;
  };
  int* gcur = (int*)carve((NB + 4) * 4);
  int* st = (int*)carve((size_t)NB * BCAP * 4);
  int* glofs = (int*)carve((size_t)NBH * GOFS * 4);
  int* glcol = (int*)carve((size_t)NBH * LCAP * 4);
  u16* w1f = (u16*)carve(8192 * 2);
  u16* w2f0 = (u16*)carve(4096 * 2);
  u16* w2f1 = (u16*)carve(4096 * 2);
  u16* w2f2 = (u16*)carve(4096 * 2);
  u16* w1nf1 = (u16*)carve(4096 * 2);
  u16* w1nf2 = (u16*)carve(4096 * 2);
  u16* zA = (u16*)carve((size_t)(NNODES + 1) * 64 * 2);
  u16* zB = (u16*)carve((size_t)(NNODES + 1) * 64 * 2);
  float* gsum = (float*)carve((size_t)NGRAPHS * 192 * 4);
  float* gmax = (float*)carve((size_t)NGRAPHS * 192 * 4);
  int* gcnt = (int*)carve(NGRAPHS * 4);

  init_kernel<<<4, 256, 0, stream>>>(gcur, zA, zB);
  hipMemsetAsync(gsum, 0, (size_t)NGRAPHS * 192 * 4 * 2, stream);
  bin_kernel<<<NCHUNKS, 512, 0, stream>>>(src, dst, gcur, st);
  csr_kernel<<<NBH, 256, 0, stream>>>(gcur, st, glofs, glcol);
  prep_kernel<<<6, 256, 0, stream>>>(lw1[0], lw2[0], lw2[1], lw2[2], lw1[1],
                                     lw1[2], w1f, w2f0, w2f1, w2f2, w1nf1,
                                     w1nf2);
  cnt_kernel<<<2, 256, 0, stream>>>(batch, gcnt);

  gemm128_kernel<<<1563, 256, 0, stream>>>(x, w1f, zA);

  agg_kernel<true><<<NBH, 256, 0, stream>>>(zA, lb1[0], w2f0, lb2[0], w1nf1,
                                            eps, 0, glofs, glcol, batch, gsum,
                                            gmax, zB);
  agg_kernel<true><<<NBH, 256, 0, stream>>>(zB, lb1[1], w2f1, lb2[1], w1nf2,
                                            eps, 1, glofs, glcol, batch, gsum,
                                            gmax, zA);
  agg_kernel<false><<<NBH, 256, 0, stream>>>(zA, lb1[2], w2f2, lb2[2],
                                             (const u16*)nullptr, eps, 2, glofs,
                                             glcol, batch, gsum, gmax,
                                             (u16*)nullptr);

  head_kernel<<<NGRAPHS / 4, 256, 0, stream>>>(gsum, gmax, gcnt, fc1w, fc1b,
                                               fc2w, fc2b, out);
}

// Round 2
// 322.257 us; speedup vs baseline: 1.1458x; 1.1052x over previous
//
#include <hip/hip_runtime.h>
#include <math.h>

// GIN v8: occupancy attack on agg_kernel. v7's 4-stream ILP was a null
// (58us, VALUBusy/occupancy unchanged) -> bottleneck is TLP, not per-wave
// ILP. agg now runs 512 threads / 8 waves per block (same 64 nodes, same
// 27.6KB LDS): wave-limit gives 4 blocks * 8 waves = 32 waves/CU (100%)
// vs ~10 before. Each wave gathers 8 nodes (simple v6.1 serial body, low
// VGPR for 8 waves/SIMD). MFMA stays on waves 0-3 (MfmaUtil was 1%);
// pooling split across 8 waves (8 rows each); two LDS_FENCEs promoted to
// __syncthreads for the new cross-wave H1/H2 hand-offs.

#define NNODES 100000
#define NEDGES 1600000
#define NGRAPHS 512
#define NB 782
#define NBH 1564
#define BCAP 2560
#define LCAP 2304
#define GOFS 72
#define CHUNK 4096
#define NCHUNKS 391
#define HSTR 72   // H1/H2 row stride (u16): 144B, 36 dwords = 4 mod 32
#define XSTR 136  // gemm x-tile row stride (u16)

typedef unsigned short u16;
typedef unsigned int u32;
typedef __attribute__((ext_vector_type(8))) short short8;
typedef __attribute__((ext_vector_type(4))) float f32x4;

__device__ __forceinline__ u16 f2b(float f) {
  union { float f; unsigned u; } v;
  v.f = f;
  unsigned r = v.u + 0x7FFF + ((v.u >> 16) & 1);
  return (u16)(r >> 16);
}
__device__ __forceinline__ float b2f(u16 h) {
  union { unsigned u; float f; } v;
  v.u = ((unsigned)h) << 16;
  return v.f;
}
#define LDS_FENCE() __asm__ volatile("s_waitcnt lgkmcnt(0)" ::: "memory")

// ---------------- init ----------------

__global__ __launch_bounds__(256) void init_kernel(int* __restrict__ gcur,
                                                   u16* __restrict__ zA,
                                                   u16* __restrict__ zB) {
  int i = blockIdx.x * 256 + threadIdx.x;
  if (i < NB) gcur[i] = i * BCAP;
  if (blockIdx.x == 3) {
    int t = threadIdx.x;
    if (t < 64) zA[(size_t)NNODES * 64 + t] = 0;
    else if (t < 128) zB[(size_t)NNODES * 64 + (t - 64)] = 0;
  }
}

// ---------------- per-graph node counts (binary search, batch sorted) -----

__device__ __forceinline__ int lb_dev(const int* __restrict__ a, int n, int v) {
  int lo = 0, hi = n;
  while (lo < hi) {
    int m = (lo + hi) >> 1;
    if (a[m] < v)
      lo = m + 1;
    else
      hi = m;
  }
  return lo;
}

__global__ __launch_bounds__(256) void cnt_kernel(const int* __restrict__ batch,
                                                  int* __restrict__ gcnt) {
  int g = blockIdx.x * 256 + threadIdx.x;
  if (g < NGRAPHS)
    gcnt[g] = lb_dev(batch, NNODES, g + 1) - lb_dev(batch, NNODES, g);
}

// ---------------- weight pre-swizzle to MFMA B-fragment order -------------

__global__ __launch_bounds__(256) void prep_kernel(
    const float* __restrict__ w1g, const float* __restrict__ w2a,
    const float* __restrict__ w2b, const float* __restrict__ w2c,
    const float* __restrict__ w1b, const float* __restrict__ w1c,
    u16* __restrict__ w1f, u16* __restrict__ w2fa, u16* __restrict__ w2fb,
    u16* __restrict__ w2fc, u16* __restrict__ w1nfb, u16* __restrict__ w1nfc) {
  int blk = blockIdx.x, tid = threadIdx.x;
  if (blk == 0) {  // 128x64
    for (int i = tid; i < 8192; i += 256) {
      int jj = i & 7, lane = (i >> 3) & 63, c = i >> 9;
      int nt = c >> 2, ks = c & 3;
      int mrow = lane & 15, quad = lane >> 4;
      w1f[i] = f2b(w1g[(ks * 32 + quad * 8 + jj) * 64 + nt * 16 + mrow]);
    }
  } else {  // 64x64
    const float* s = (blk == 1) ? w2a : (blk == 2) ? w2b : (blk == 3) ? w2c
                    : (blk == 4) ? w1b : w1c;
    u16* d = (blk == 1) ? w2fa : (blk == 2) ? w2fb : (blk == 3) ? w2fc
             : (blk == 4) ? w1nfb : w1nfc;
    for (int i = tid; i < 4096; i += 256) {
      int jj = i & 7, lane = (i >> 3) & 63, c = i >> 9;
      int nt = c >> 1, ks = c & 1;
      int mrow = lane & 15, quad = lane >> 4;
      d[i] = f2b(s[(ks * 32 + quad * 8 + jj) * 64 + nt * 16 + mrow]);
    }
  }
}

// ---------------- binned scatter ----------------

__global__ __launch_bounds__(512) void bin_kernel(const int* __restrict__ src,
                                                  const int* __restrict__ dst,
                                                  int* __restrict__ gcur,
                                                  int* __restrict__ st) {
  __shared__ int hist[NB];
  __shared__ int lofs[NB + 1];
  __shared__ int lcur[NB];
  __shared__ int gbase[NB];
  __shared__ int sd[1024];
  __shared__ int staged[CHUNK];
  __shared__ u16 stb[CHUNK];
  const int t = threadIdx.x;
  const int e0 = blockIdx.x * CHUNK;
  const int n = min(CHUNK, NEDGES - e0);

  for (int i = t; i < NB; i += 512) hist[i] = 0;
  __syncthreads();

  int pk[8];
  int bk[8];
#pragma unroll
  for (int k = 0; k < 8; ++k) {
    int i = t + k * 512;
    if (i < n) {
      int s = src[e0 + i];
      int d = dst[e0 + i];
      int b = d >> 7;
      pk[k] = (s << 7) | (d & 127);
      bk[k] = b;
      atomicAdd(&hist[b], 1);
    } else {
      bk[k] = -1;
    }
  }
  __syncthreads();

  sd[t] = (t < NB) ? hist[t] : 0;
  sd[t + 512] = (t + 512 < NB) ? hist[t + 512] : 0;
  __syncthreads();
  for (int off = 1; off < 1024; off <<= 1) {
    int v0 = (t >= off) ? sd[t - off] : 0;
    int v1 = (t + 512 >= off) ? sd[t + 512 - off] : 0;
    __syncthreads();
    sd[t] += v0;
    sd[t + 512] += v1;
    __syncthreads();
  }
  if (t == 0) lofs[0] = 0;
  for (int i = t; i < NB; i += 512) {
    int inc = sd[i];
    int c = hist[i];
    lofs[i + 1] = inc;
    lcur[i] = inc - c;
    gbase[i] = c ? atomicAdd(&gcur[i], c) : 0;
  }
  __syncthreads();

#pragma unroll
  for (int k = 0; k < 8; ++k) {
    if (bk[k] >= 0) {
      int r = atomicAdd(&lcur[bk[k]], 1);
      staged[r] = pk[k];
      stb[r] = (u16)bk[k];
    }
  }
  __syncthreads();

  for (int i = t; i < n; i += 512) {
    int b = stb[i];
    st[gbase[b] + (i - lofs[b])] = staged[i];
  }
}

// ---------------- CSR build (once) ----------------

__global__ __launch_bounds__(256) void csr_kernel(const int* __restrict__ gcur,
                                                  const int* __restrict__ st,
                                                  int* __restrict__ glofs,
                                                  int* __restrict__ glcol) {
  __shared__ int lcol[LCAP];
  __shared__ int lhist[64];
  __shared__ int lofs[65];
  __shared__ int lcur[64];
  __shared__ int ssc[64];
  const int tid = threadIdx.x;
  const int blk = blockIdx.x;
  const int bkt = blk >> 1;
  const int half = blk & 1;
  const int ofs = bkt * BCAP;
  const int cnt = min(gcur[bkt] - ofs, BCAP);

  if (tid < 64) lhist[tid] = 0;
  __syncthreads();
  for (int i = tid; i < cnt; i += 256) {
    int d7 = st[ofs + i] & 127;
    if ((d7 >> 6) == half) atomicAdd(&lhist[d7 & 63], 1);
  }
  __syncthreads();
  if (tid < 64) ssc[tid] = (lhist[tid] + 15) & ~15;
  __syncthreads();
  for (int off = 1; off < 64; off <<= 1) {
    int v = (tid < 64 && tid >= off) ? ssc[tid - off] : 0;
    __syncthreads();
    if (tid < 64) ssc[tid] += v;
    __syncthreads();
  }
  if (tid < 64) {
    lofs[tid + 1] = ssc[tid];
    lcur[tid] = ssc[tid] - ((lhist[tid] + 15) & ~15);
  }
  if (tid == 0) lofs[0] = 0;
  __syncthreads();
  for (int i = tid; i < cnt; i += 256) {
    int p = st[ofs + i];
    int d7 = p & 127;
    if ((d7 >> 6) == half) {
      int r = atomicAdd(&lcur[d7 & 63], 1);
      if (r < LCAP) lcol[r] = p >> 7;
    }
  }
  __syncthreads();
  if (tid < 64) {
    int re = min(lofs[tid + 1], LCAP);
    for (int r = lcur[tid]; r < re; ++r) lcol[r] = NNODES;
  }
  __syncthreads();
  if (tid < 65) glofs[blk * GOFS + tid] = min(lofs[tid], LCAP);
  int L = min(lofs[64], LCAP);
  int4* gdst = (int4*)(glcol + (size_t)blk * LCAP);
  const int4* lsrc = (const int4*)lcol;
  for (int i = tid; i < (L >> 2); i += 256) gdst[i] = lsrc[i];
}

// ---------------- GEMM (MFMA): z = x(Nx128) @ w1, z bf16 ----------------

__global__ __launch_bounds__(256) void gemm128_kernel(
    const float* __restrict__ x, const u16* __restrict__ w1f,
    u16* __restrict__ z) {
  __shared__ u16 w1h[128 * 64];  // fragment order, 16 KB
  __shared__ u16 Xt[64 * XSTR];  // 17 KB; reused as z-tile
  const int tid = threadIdx.x;
  const int base = blockIdx.x * 64;
  for (int i = tid; i < 1024; i += 256) ((int4*)w1h)[i] = ((const int4*)w1f)[i];
  for (int i = tid; i < 2048; i += 256) {
    int n = i >> 5, c4 = i & 31;
    int nn = base + n;
    float4 v = make_float4(0.f, 0.f, 0.f, 0.f);
    if (nn < NNODES) v = *(const float4*)&x[(size_t)nn * 128 + 4 * c4];
    u32 p0 = (u32)f2b(v.x) | ((u32)f2b(v.y) << 16);
    u32 p1 = (u32)f2b(v.z) | ((u32)f2b(v.w) << 16);
    *(u32*)&Xt[n * XSTR + 4 * c4] = p0;
    *(u32*)&Xt[n * XSTR + 4 * c4 + 2] = p1;
  }
  __syncthreads();
  const int lane = tid & 63;
  const int wv = tid >> 6;
  const int mrow = lane & 15;
  const int quad = lane >> 4;
  f32x4 accs[4];
#pragma unroll
  for (int nt = 0; nt < 4; ++nt) {
    f32x4 acc = {0.f, 0.f, 0.f, 0.f};
#pragma unroll
    for (int ks = 0; ks < 4; ++ks) {
      short8 afr = *(const short8*)&Xt[(wv * 16 + mrow) * XSTR + ks * 32 + quad * 8];
      short8 bfr = *(const short8*)&w1h[((nt * 4 + ks) * 64 + lane) * 8];
      acc = __builtin_amdgcn_mfma_f32_16x16x32_bf16(afr, bfr, acc, 0, 0, 0);
    }
    accs[nt] = acc;
  }
  __syncthreads();
  u16* Zt = Xt;
#pragma unroll
  for (int nt = 0; nt < 4; ++nt)
#pragma unroll
    for (int r = 0; r < 4; ++r)
      Zt[(wv * 16 + quad * 4 + r) * HSTR + nt * 16 + mrow] = f2b(accs[nt][r]);
  __syncthreads();
  for (int i = tid; i < 2048; i += 256) {
    int n = i >> 5, kk = i & 31;
    int nn = base + n;
    if (nn < NNODES) *(u32*)&z[(size_t)nn * 64 + 2 * kk] = *(u32*)&Zt[n * HSTR + 2 * kk];
  }
}

// ---------------- agg v8: 8-wave block (TLP), gather 8 nodes/wave ---------

template <bool HAS_NEXT>
__global__ __launch_bounds__(512, 8) void agg_kernel(
    const u16* __restrict__ zin, const float* __restrict__ b1,
    const u16* __restrict__ w2f, const float* __restrict__ b2,
    const u16* __restrict__ w1nf, const float* __restrict__ eps, int li,
    const int* __restrict__ glofs, const int* __restrict__ glcol,
    const int* __restrict__ batch, float* __restrict__ gsum,
    float* __restrict__ gmax, u16* __restrict__ zn) {
  __shared__ u16 w2h[64 * 64];  // fragment order, 8 KB
  __shared__ float b2s[64];
  __shared__ int lofs[65];
  __shared__ int bt[64];
  __shared__ __align__(16) char scratch[2 * 64 * HSTR * 2];  // 18432 B
  int* lcol = (int*)scratch;                   // 9216 B, dead after gather
  u16* H2 = (u16*)scratch;                     // first region (post-gather)
  u16* H1 = (u16*)(scratch + 64 * HSTR * 2);   // second region (gather-live)
  u16* w1nh = (u16*)(scratch + 64 * HSTR * 2); // aliases H1 after matmul1
  const int tid = threadIdx.x;
  const int lane = tid & 63;
  const int wv = tid >> 6;  // 0..7
  const int sub = lane >> 5;
  const int fl = lane & 31;
  const int f = 2 * fl + sub;
  const int blk = blockIdx.x;
  const int base = ((blk >> 1) << 7) + ((blk & 1) << 6);

  for (int i = tid; i < 512; i += 512) ((int4*)w2h)[i] = ((const int4*)w2f)[i];
  if (tid < 64) {
    b2s[tid] = b2[tid];
    int nn = base + tid;
    bt[tid] = (nn < NNODES) ? batch[nn] : -1;
  }
  if (tid < 65) lofs[tid] = glofs[blk * GOFS + tid];
  __syncthreads();
  const int L = lofs[64];
  {
    int4* ldst = (int4*)lcol;
    const int4* gsrc = (const int4*)(glcol + (size_t)blk * LCAP);
    for (int i = tid; i < (L >> 2); i += 512) ldst[i] = gsrc[i];
  }
  __syncthreads();

  const float e1 = 1.0f + eps[li];
  const float b1v = b1[f];
  const int n0g = wv * 8;  // 8 nodes per wave

#pragma unroll 1
  for (int j = 0; j < 8; ++j) {
    int ln = n0g + j;
    int nn = base + ln;
    int sn = (nn < NNODES) ? nn : NNODES;
    int rs = lofs[ln], re = lofs[ln + 1];
    float sa0 = 0.f, sa1 = 0.f, sa2 = 0.f, sa3 = 0.f;
    float sb0 = 0.f, sb1 = 0.f, sb2 = 0.f, sb3 = 0.f;
    for (int e = rs; e < re; e += 16) {
      int c0 = lcol[e + 0 + sub];
      int c1 = lcol[e + 2 + sub];
      int c2 = lcol[e + 4 + sub];
      int c3 = lcol[e + 6 + sub];
      int c4 = lcol[e + 8 + sub];
      int c5 = lcol[e + 10 + sub];
      int c6 = lcol[e + 12 + sub];
      int c7 = lcol[e + 14 + sub];
      u32 v0 = *(const u32*)&zin[(size_t)c0 * 64 + 2 * fl];
      u32 v1 = *(const u32*)&zin[(size_t)c1 * 64 + 2 * fl];
      u32 v2 = *(const u32*)&zin[(size_t)c2 * 64 + 2 * fl];
      u32 v3 = *(const u32*)&zin[(size_t)c3 * 64 + 2 * fl];
      u32 v4 = *(const u32*)&zin[(size_t)c4 * 64 + 2 * fl];
      u32 v5 = *(const u32*)&zin[(size_t)c5 * 64 + 2 * fl];
      u32 v6 = *(const u32*)&zin[(size_t)c6 * 64 + 2 * fl];
      u32 v7 = *(const u32*)&zin[(size_t)c7 * 64 + 2 * fl];
      sa0 += __uint_as_float(v0 << 16);
      sb0 += __uint_as_float(v0 & 0xffff0000u);
      sa1 += __uint_as_float(v1 << 16);
      sb1 += __uint_as_float(v1 & 0xffff0000u);
      sa2 += __uint_as_float(v2 << 16);
      sb2 += __uint_as_float(v2 & 0xffff0000u);
      sa3 += __uint_as_float(v3 << 16);
      sb3 += __uint_as_float(v3 & 0xffff0000u);
      sa0 += __uint_as_float(v4 << 16);
      sb0 += __uint_as_float(v4 & 0xffff0000u);
      sa1 += __uint_as_float(v5 << 16);
      sb1 += __uint_as_float(v5 & 0xffff0000u);
      sa2 += __uint_as_float(v6 << 16);
      sb2 += __uint_as_float(v6 & 0xffff0000u);
      sa3 += __uint_as_float(v7 << 16);
      sb3 += __uint_as_float(v7 & 0xffff0000u);
    }
    float sa = (sa0 + sa1) + (sa2 + sa3);
    float sb = (sb0 + sb1) + (sb2 + sb3);
    sa += __shfl_xor(sa, 32);
    sb += __shfl_xor(sb, 32);
    float sum = sub ? sb : sa;
    float self = b2f(zin[(size_t)sn * 64 + f]);
    float h = fmaxf(sum + e1 * self + b1v, 0.f);  // h1
    H1[ln * HSTR + f] = f2b(h);                   // H1 disjoint from lcol
  }
  __syncthreads();  // lcol reads done block-wide; H1 fully written

  const int mrow = lane & 15;
  const int quad = lane >> 4;
  if (wv < 4) {
    // matmul1: H2 = relu(H1 @ w2 + b2)  (A rows = 16-row quarter wv)
    f32x4 m1[4];
#pragma unroll
    for (int nt = 0; nt < 4; ++nt) {
      f32x4 acc = {0.f, 0.f, 0.f, 0.f};
#pragma unroll
      for (int ks = 0; ks < 2; ++ks) {
        short8 afr = *(const short8*)&H1[(wv * 16 + mrow) * HSTR + ks * 32 + quad * 8];
        short8 bfr = *(const short8*)&w2h[((nt * 2 + ks) * 64 + lane) * 8];
        acc = __builtin_amdgcn_mfma_f32_16x16x32_bf16(afr, bfr, acc, 0, 0, 0);
      }
      m1[nt] = acc;
    }
    LDS_FENCE();
#pragma unroll
    for (int nt = 0; nt < 4; ++nt) {
      float bb = b2s[nt * 16 + mrow];
#pragma unroll
      for (int r = 0; r < 4; ++r)
        H2[(wv * 16 + quad * 4 + r) * HSTR + nt * 16 + mrow] =
            f2b(fmaxf(m1[nt][r] + bb, 0.f));
    }
  }
  __syncthreads();  // H2 visible to all waves for pooling

  // fused pooling: wave wv owns rows wv*8..wv*8+7 of H2, lane = feature
  {
    const int n0p = wv * 8;
    float s = 0.f, m = 0.f;
    int cur = bt[n0p];
#pragma unroll 1
    for (int j = 0; j < 8; ++j) {
      int b = bt[n0p + j];
      if (b != cur) {
        if (cur >= 0) {
          atomicAdd(&gsum[cur * 192 + li * 64 + lane], s);
          atomicMax((u32*)&gmax[cur * 192 + li * 64 + lane], __float_as_uint(m));
        }
        s = 0.f;
        m = 0.f;
        cur = b;
      }
      if (b >= 0) {
        float v = b2f(H2[(n0p + j) * HSTR + lane]);
        s += v;
        m = fmaxf(m, v);
      }
    }
    if (cur >= 0) {
      atomicAdd(&gsum[cur * 192 + li * 64 + lane], s);
      atomicMax((u32*)&gmax[cur * 192 + li * 64 + lane], __float_as_uint(m));
    }
  }

  if (HAS_NEXT) {
    __syncthreads();  // pooling reads of H2 done; H1 fully dead
    for (int i = tid; i < 512; i += 512)
      ((int4*)w1nh)[i] = ((const int4*)w1nf)[i];
    __syncthreads();
    if (wv < 4) {
      // matmul2: zn = H2 @ w1n (A rows = own 16-row quarter)
      f32x4 m2[4];
#pragma unroll
      for (int nt = 0; nt < 4; ++nt) {
        f32x4 acc = {0.f, 0.f, 0.f, 0.f};
#pragma unroll
        for (int ks = 0; ks < 2; ++ks) {
          short8 afr = *(const short8*)&H2[(wv * 16 + mrow) * HSTR + ks * 32 + quad * 8];
          short8 bfr = *(const short8*)&w1nh[((nt * 2 + ks) * 64 + lane) * 8];
          acc = __builtin_amdgcn_mfma_f32_16x16x32_bf16(afr, bfr, acc, 0, 0, 0);
        }
        m2[nt] = acc;
      }
      LDS_FENCE();  // all A-reads of own H2 rows done before overwrite
#pragma unroll
      for (int nt = 0; nt < 4; ++nt)
#pragma unroll
        for (int r = 0; r < 4; ++r)
          H2[(wv * 16 + quad * 4 + r) * HSTR + nt * 16 + mrow] = f2b(m2[nt][r]);
    }
    __syncthreads();
    for (int i = tid; i < 2048; i += 512) {
      int n = i >> 5, kk = i & 31;
      int nn = base + n;
      if (nn < NNODES)
        *(u32*)&zn[(size_t)nn * 64 + 2 * kk] = *(u32*)&H2[n * HSTR + 2 * kk];
    }
  }
}

// ---------------- Head: pooled stats -> fc1 -> fc2 -> sigmoid -------------

__global__ __launch_bounds__(256) void head_kernel(
    const float* __restrict__ gsum, const float* __restrict__ gmax,
    const int* __restrict__ gcnt, const float* __restrict__ fc1w,
    const float* __restrict__ fc1b, const float* __restrict__ fc2w,
    const float* __restrict__ fc2b, float* __restrict__ out) {
  __shared__ float gs[4 * 576];
  int tid = threadIdx.x;
  int g0 = blockIdx.x * 4;
  for (int i = tid; i < 4 * 192; i += 256) {
    int w = i / 192, idx = i - w * 192;
    int gi = g0 + w;
    float S = gsum[gi * 192 + idx];
    float M = gmax[gi * 192 + idx];
    float C = (float)gcnt[gi];
    gs[w * 576 + idx] = S / fmaxf(C, 1.0f);
    gs[w * 576 + 192 + idx] = M;
    gs[w * 576 + 384 + idx] = S;
  }
  __syncthreads();
  int wv = tid >> 6, lane = tid & 63;
  int gi = g0 + wv;
  const float* grow = &gs[wv * 576];
  float acc = fc1b[lane];
#pragma unroll 8
  for (int k = 0; k < 576; ++k) acc += grow[k] * fc1w[k * 64 + lane];
  acc = fmaxf(acc, 0.f);
  float p0 = acc * fc2w[lane * 2 + 0];
  float p1 = acc * fc2w[lane * 2 + 1];
  for (int off = 32; off; off >>= 1) {
    p0 += __shfl_down(p0, off);
    p1 += __shfl_down(p1, off);
  }
  if (lane == 0) {
    out[gi * 2 + 0] = 1.f / (1.f + __expf(-(p0 + fc2b[0])));
    out[gi * 2 + 1] = 1.f / (1.f + __expf(-(p1 + fc2b[1])));
  }
}

// ---------------- launch ----------------

extern "C" void kernel_launch(void* const* d_in, const int* in_sizes, int n_in,
                              void* d_out, int out_size, void* d_ws,
                              size_t ws_size, hipStream_t stream) {
  const float* x = (const float*)d_in[0];
  const int* ei = (const int*)d_in[1];
  const int* src = ei;
  const int* dst = ei + NEDGES;
  const int* batch = (const int*)d_in[2];
  const float* lw1[3] = {(const float*)d_in[3], (const float*)d_in[7],
                         (const float*)d_in[11]};
  const float* lb1[3] = {(const float*)d_in[4], (const float*)d_in[8],
                         (const float*)d_in[12]};
  const float* lw2[3] = {(const float*)d_in[5], (const float*)d_in[9],
                         (const float*)d_in[13]};
  const float* lb2[3] = {(const float*)d_in[6], (const float*)d_in[10],
                         (const float*)d_in[14]};
  const float* eps = (const float*)d_in[15];
  const float* fc1w = (const float*)d_in[16];
  const float* fc1b = (const float*)d_in[17];
  const float* fc2w = (const float*)d_in[18];
  const float* fc2b = (const float*)d_in[19];
  float* out = (float*)d_out;

  char* p = (char*)d_ws;
  auto carve = [&](size_t bytes) {
    void* r = (void*)p;
    p += (bytes + 1023) & ~(size_t)1023;
    return r;
  };
  int* gcur = (int*)carve((NB + 4) * 4);
  int* st = (int*)carve((size_t)NB * BCAP * 4);
  int* glofs = (int*)carve((size_t)NBH * GOFS * 4);
  int* glcol = (int*)carve((size_t)NBH * LCAP * 4);
  u16* w1f = (u16*)carve(8192 * 2);
  u16* w2f0 = (u16*)carve(4096 * 2);
  u16* w2f1 = (u16*)carve(4096 * 2);
  u16* w2f2 = (u16*)carve(4096 * 2);
  u16* w1nf1 = (u16*)carve(4096 * 2);
  u16* w1nf2 = (u16*)carve(4096 * 2);
  u16* zA = (u16*)carve((size_t)(NNODES + 1) * 64 * 2);
  u16* zB = (u16*)carve((size_t)(NNODES + 1) * 64 * 2);
  float* gsum = (float*)carve((size_t)NGRAPHS * 192 * 4);
  float* gmax = (float*)carve((size_t)NGRAPHS * 192 * 4);
  int* gcnt = (int*)carve(NGRAPHS * 4);

  init_kernel<<<4, 256, 0, stream>>>(gcur, zA, zB);
  hipMemsetAsync(gsum, 0, (size_t)NGRAPHS * 192 * 4 * 2, stream);
  bin_kernel<<<NCHUNKS, 512, 0, stream>>>(src, dst, gcur, st);
  csr_kernel<<<NBH, 256, 0, stream>>>(gcur, st, glofs, glcol);
  prep_kernel<<<6, 256, 0, stream>>>(lw1[0], lw2[0], lw2[1], lw2[2], lw1[1],
                                     lw1[2], w1f, w2f0, w2f1, w2f2, w1nf1,
                                     w1nf2);
  cnt_kernel<<<2, 256, 0, stream>>>(batch, gcnt);

  gemm128_kernel<<<1563, 256, 0, stream>>>(x, w1f, zA);

  agg_kernel<true><<<NBH, 512, 0, stream>>>(zA, lb1[0], w2f0, lb2[0], w1nf1,
                                            eps, 0, glofs, glcol, batch, gsum,
                                            gmax, zB);
  agg_kernel<true><<<NBH, 512, 0, stream>>>(zB, lb1[1], w2f1, lb2[1], w1nf2,
                                            eps, 1, glofs, glcol, batch, gsum,
                                            gmax, zA);
  agg_kernel<false><<<NBH, 512, 0, stream>>>(zA, lb1[2], w2f2, lb2[2],
                                             (const u16*)nullptr, eps, 2, glofs,
                                             glcol, batch, gsum, gmax,
                                             (u16*)nullptr);

  head_kernel<<<NGRAPHS / 4, 256, 0, stream>>>(gsum, gmax, gcnt, fc1w, fc1b,
                                               fc2w, fc2b, out);
}

// Round 3
// 319.819 us; speedup vs baseline: 1.1545x; 1.0076x over previous
//
#include <hip/hip_runtime.h>
#include <math.h>

// GIN v9: wide gather (x4 rows per load) in agg_kernel.
// v8 established TLP (8 waves, occ 56%, 44us) but VGPR=24 shows the
// compiler didn't pipeline the e-loop: 8 ds_read + 8 narrow loads per
// 16 edges, serial chain. v9: each lane loads dwordx2 (8B), 16 lanes
// cover a 128B row -> 4 rows per load instr. Per 16-edge iter: 4 ds_read
// + 4 addr + 4 loads + 32 unpack/add. 4 accumulators/lane; butterfly
// reduce (xor 16,32); quarter-0 lanes write H1 rows. Same traffic.
// Also: init+cnt+prep fused into setup_kernel (-2 launches).

#define NNODES 100000
#define NEDGES 1600000
#define NGRAPHS 512
#define NB 782
#define NBH 1564
#define BCAP 2560
#define LCAP 2304
#define GOFS 72
#define CHUNK 4096
#define NCHUNKS 391
#define HSTR 72   // H1/H2 row stride (u16): 144B, 36 dwords = 4 mod 32
#define XSTR 136  // gemm x-tile row stride (u16)

typedef unsigned short u16;
typedef unsigned int u32;
typedef unsigned long long u64;
typedef __attribute__((ext_vector_type(8))) short short8;
typedef __attribute__((ext_vector_type(4))) float f32x4;

__device__ __forceinline__ u16 f2b(float f) {
  union { float f; unsigned u; } v;
  v.f = f;
  unsigned r = v.u + 0x7FFF + ((v.u >> 16) & 1);
  return (u16)(r >> 16);
}
__device__ __forceinline__ float b2f(u16 h) {
  union { unsigned u; float f; } v;
  v.u = ((unsigned)h) << 16;
  return v.f;
}
#define LDS_FENCE() __asm__ volatile("s_waitcnt lgkmcnt(0)" ::: "memory")

// ---------------- fused setup: init + cnt + weight pre-swizzle ------------

__device__ __forceinline__ int lb_dev(const int* __restrict__ a, int n, int v) {
  int lo = 0, hi = n;
  while (lo < hi) {
    int m = (lo + hi) >> 1;
    if (a[m] < v)
      lo = m + 1;
    else
      hi = m;
  }
  return lo;
}

__global__ __launch_bounds__(256) void setup_kernel(
    int* __restrict__ gcur, u16* __restrict__ zA, u16* __restrict__ zB,
    const int* __restrict__ batch, int* __restrict__ gcnt,
    const float* __restrict__ w1g, const float* __restrict__ w2a,
    const float* __restrict__ w2b, const float* __restrict__ w2c,
    const float* __restrict__ w1b, const float* __restrict__ w1c,
    u16* __restrict__ w1f, u16* __restrict__ w2fa, u16* __restrict__ w2fb,
    u16* __restrict__ w2fc, u16* __restrict__ w1nfb, u16* __restrict__ w1nfc) {
  int blk = blockIdx.x, tid = threadIdx.x;
  if (blk == 0) {  // w1: 128x64
    for (int i = tid; i < 8192; i += 256) {
      int jj = i & 7, lane = (i >> 3) & 63, c = i >> 9;
      int nt = c >> 2, ks = c & 3;
      int mrow = lane & 15, quad = lane >> 4;
      w1f[i] = f2b(w1g[(ks * 32 + quad * 8 + jj) * 64 + nt * 16 + mrow]);
    }
  } else if (blk < 6) {  // 64x64 weights
    const float* s = (blk == 1) ? w2a : (blk == 2) ? w2b : (blk == 3) ? w2c
                    : (blk == 4) ? w1b : w1c;
    u16* d = (blk == 1) ? w2fa : (blk == 2) ? w2fb : (blk == 3) ? w2fc
             : (blk == 4) ? w1nfb : w1nfc;
    for (int i = tid; i < 4096; i += 256) {
      int jj = i & 7, lane = (i >> 3) & 63, c = i >> 9;
      int nt = c >> 1, ks = c & 1;
      int mrow = lane & 15, quad = lane >> 4;
      d[i] = f2b(s[(ks * 32 + quad * 8 + jj) * 64 + nt * 16 + mrow]);
    }
  } else if (blk == 6) {  // init
    for (int i = tid; i < NB; i += 256) gcur[i] = i * BCAP;
    if (tid < 64) zA[(size_t)NNODES * 64 + tid] = 0;
    else if (tid < 128) zB[(size_t)NNODES * 64 + (tid - 64)] = 0;
  } else {  // cnt (batch sorted -> binary search)
    for (int g = tid; g < NGRAPHS; g += 256)
      gcnt[g] = lb_dev(batch, NNODES, g + 1) - lb_dev(batch, NNODES, g);
  }
}

// ---------------- binned scatter ----------------

__global__ __launch_bounds__(512) void bin_kernel(const int* __restrict__ src,
                                                  const int* __restrict__ dst,
                                                  int* __restrict__ gcur,
                                                  int* __restrict__ st) {
  __shared__ int hist[NB];
  __shared__ int lofs[NB + 1];
  __shared__ int lcur[NB];
  __shared__ int gbase[NB];
  __shared__ int sd[1024];
  __shared__ int staged[CHUNK];
  __shared__ u16 stb[CHUNK];
  const int t = threadIdx.x;
  const int e0 = blockIdx.x * CHUNK;
  const int n = min(CHUNK, NEDGES - e0);

  for (int i = t; i < NB; i += 512) hist[i] = 0;
  __syncthreads();

  int pk[8];
  int bk[8];
#pragma unroll
  for (int k = 0; k < 8; ++k) {
    int i = t + k * 512;
    if (i < n) {
      int s = src[e0 + i];
      int d = dst[e0 + i];
      int b = d >> 7;
      pk[k] = (s << 7) | (d & 127);
      bk[k] = b;
      atomicAdd(&hist[b], 1);
    } else {
      bk[k] = -1;
    }
  }
  __syncthreads();

  sd[t] = (t < NB) ? hist[t] : 0;
  sd[t + 512] = (t + 512 < NB) ? hist[t + 512] : 0;
  __syncthreads();
  for (int off = 1; off < 1024; off <<= 1) {
    int v0 = (t >= off) ? sd[t - off] : 0;
    int v1 = (t + 512 >= off) ? sd[t + 512 - off] : 0;
    __syncthreads();
    sd[t] += v0;
    sd[t + 512] += v1;
    __syncthreads();
  }
  if (t == 0) lofs[0] = 0;
  for (int i = t; i < NB; i += 512) {
    int inc = sd[i];
    int c = hist[i];
    lofs[i + 1] = inc;
    lcur[i] = inc - c;
    gbase[i] = c ? atomicAdd(&gcur[i], c) : 0;
  }
  __syncthreads();

#pragma unroll
  for (int k = 0; k < 8; ++k) {
    if (bk[k] >= 0) {
      int r = atomicAdd(&lcur[bk[k]], 1);
      staged[r] = pk[k];
      stb[r] = (u16)bk[k];
    }
  }
  __syncthreads();

  for (int i = t; i < n; i += 512) {
    int b = stb[i];
    st[gbase[b] + (i - lofs[b])] = staged[i];
  }
}

// ---------------- CSR build (once) ----------------

__global__ __launch_bounds__(256) void csr_kernel(const int* __restrict__ gcur,
                                                  const int* __restrict__ st,
                                                  int* __restrict__ glofs,
                                                  int* __restrict__ glcol) {
  __shared__ int lcol[LCAP];
  __shared__ int lhist[64];
  __shared__ int lofs[65];
  __shared__ int lcur[64];
  __shared__ int ssc[64];
  const int tid = threadIdx.x;
  const int blk = blockIdx.x;
  const int bkt = blk >> 1;
  const int half = blk & 1;
  const int ofs = bkt * BCAP;
  const int cnt = min(gcur[bkt] - ofs, BCAP);

  if (tid < 64) lhist[tid] = 0;
  __syncthreads();
  for (int i = tid; i < cnt; i += 256) {
    int d7 = st[ofs + i] & 127;
    if ((d7 >> 6) == half) atomicAdd(&lhist[d7 & 63], 1);
  }
  __syncthreads();
  if (tid < 64) ssc[tid] = (lhist[tid] + 15) & ~15;
  __syncthreads();
  for (int off = 1; off < 64; off <<= 1) {
    int v = (tid < 64 && tid >= off) ? ssc[tid - off] : 0;
    __syncthreads();
    if (tid < 64) ssc[tid] += v;
    __syncthreads();
  }
  if (tid < 64) {
    lofs[tid + 1] = ssc[tid];
    lcur[tid] = ssc[tid] - ((lhist[tid] + 15) & ~15);
  }
  if (tid == 0) lofs[0] = 0;
  __syncthreads();
  for (int i = tid; i < cnt; i += 256) {
    int p = st[ofs + i];
    int d7 = p & 127;
    if ((d7 >> 6) == half) {
      int r = atomicAdd(&lcur[d7 & 63], 1);
      if (r < LCAP) lcol[r] = p >> 7;
    }
  }
  __syncthreads();
  if (tid < 64) {
    int re = min(lofs[tid + 1], LCAP);
    for (int r = lcur[tid]; r < re; ++r) lcol[r] = NNODES;
  }
  __syncthreads();
  if (tid < 65) glofs[blk * GOFS + tid] = min(lofs[tid], LCAP);
  int L = min(lofs[64], LCAP);
  int4* gdst = (int4*)(glcol + (size_t)blk * LCAP);
  const int4* lsrc = (const int4*)lcol;
  for (int i = tid; i < (L >> 2); i += 256) gdst[i] = lsrc[i];
}

// ---------------- GEMM (MFMA): z = x(Nx128) @ w1, z bf16 ----------------

__global__ __launch_bounds__(256) void gemm128_kernel(
    const float* __restrict__ x, const u16* __restrict__ w1f,
    u16* __restrict__ z) {
  __shared__ u16 w1h[128 * 64];  // fragment order, 16 KB
  __shared__ u16 Xt[64 * XSTR];  // 17 KB; reused as z-tile
  const int tid = threadIdx.x;
  const int base = blockIdx.x * 64;
  for (int i = tid; i < 1024; i += 256) ((int4*)w1h)[i] = ((const int4*)w1f)[i];
  for (int i = tid; i < 2048; i += 256) {
    int n = i >> 5, c4 = i & 31;
    int nn = base + n;
    float4 v = make_float4(0.f, 0.f, 0.f, 0.f);
    if (nn < NNODES) v = *(const float4*)&x[(size_t)nn * 128 + 4 * c4];
    u32 p0 = (u32)f2b(v.x) | ((u32)f2b(v.y) << 16);
    u32 p1 = (u32)f2b(v.z) | ((u32)f2b(v.w) << 16);
    *(u32*)&Xt[n * XSTR + 4 * c4] = p0;
    *(u32*)&Xt[n * XSTR + 4 * c4 + 2] = p1;
  }
  __syncthreads();
  const int lane = tid & 63;
  const int wv = tid >> 6;
  const int mrow = lane & 15;
  const int quad = lane >> 4;
  f32x4 accs[4];
#pragma unroll
  for (int nt = 0; nt < 4; ++nt) {
    f32x4 acc = {0.f, 0.f, 0.f, 0.f};
#pragma unroll
    for (int ks = 0; ks < 4; ++ks) {
      short8 afr = *(const short8*)&Xt[(wv * 16 + mrow) * XSTR + ks * 32 + quad * 8];
      short8 bfr = *(const short8*)&w1h[((nt * 4 + ks) * 64 + lane) * 8];
      acc = __builtin_amdgcn_mfma_f32_16x16x32_bf16(afr, bfr, acc, 0, 0, 0);
    }
    accs[nt] = acc;
  }
  __syncthreads();
  u16* Zt = Xt;
#pragma unroll
  for (int nt = 0; nt < 4; ++nt)
#pragma unroll
    for (int r = 0; r < 4; ++r)
      Zt[(wv * 16 + quad * 4 + r) * HSTR + nt * 16 + mrow] = f2b(accs[nt][r]);
  __syncthreads();
  for (int i = tid; i < 2048; i += 256) {
    int n = i >> 5, kk = i & 31;
    int nn = base + n;
    if (nn < NNODES) *(u32*)&z[(size_t)nn * 64 + 2 * kk] = *(u32*)&Zt[n * HSTR + 2 * kk];
  }
}

// ---------------- agg v9: 8-wave block, x4-wide gather --------------------

template <bool HAS_NEXT>
__global__ __launch_bounds__(512, 8) void agg_kernel(
    const u16* __restrict__ zin, const float* __restrict__ b1,
    const u16* __restrict__ w2f, const float* __restrict__ b2,
    const u16* __restrict__ w1nf, const float* __restrict__ eps, int li,
    const int* __restrict__ glofs, const int* __restrict__ glcol,
    const int* __restrict__ batch, float* __restrict__ gsum,
    float* __restrict__ gmax, u16* __restrict__ zn) {
  __shared__ u16 w2h[64 * 64];  // fragment order, 8 KB
  __shared__ float b2s[64];
  __shared__ int lofs[65];
  __shared__ int bt[64];
  __shared__ __align__(16) char scratch[2 * 64 * HSTR * 2];  // 18432 B
  int* lcol = (int*)scratch;                   // 9216 B, dead after gather
  u16* H2 = (u16*)scratch;                     // first region (post-gather)
  u16* H1 = (u16*)(scratch + 64 * HSTR * 2);   // second region (gather-live)
  u16* w1nh = (u16*)(scratch + 64 * HSTR * 2); // aliases H1 after matmul1
  const int tid = threadIdx.x;
  const int lane = tid & 63;
  const int wv = tid >> 6;  // 0..7
  const int q = lane >> 4;   // row-quarter 0..3
  const int fq = lane & 15;  // 4-feature slot
  const int blk = blockIdx.x;
  const int base = ((blk >> 1) << 7) + ((blk & 1) << 6);

  for (int i = tid; i < 512; i += 512) ((int4*)w2h)[i] = ((const int4*)w2f)[i];
  if (tid < 64) {
    b2s[tid] = b2[tid];
    int nn = base + tid;
    bt[tid] = (nn < NNODES) ? batch[nn] : -1;
  }
  if (tid < 65) lofs[tid] = glofs[blk * GOFS + tid];
  __syncthreads();
  const int L = lofs[64];
  {
    int4* ldst = (int4*)lcol;
    const int4* gsrc = (const int4*)(glcol + (size_t)blk * LCAP);
    for (int i = tid; i < (L >> 2); i += 512) ldst[i] = gsrc[i];
  }
  __syncthreads();

  const float e1 = 1.0f + eps[li];
  const float4 b1v4 = *(const float4*)&b1[4 * fq];
  const int n0g = wv * 8;  // 8 nodes per wave

#pragma unroll 1
  for (int j = 0; j < 8; ++j) {
    int ln = n0g + j;
    int nn = base + ln;
    int sn = (nn < NNODES) ? nn : NNODES;
    int rs = lofs[ln], re = lofs[ln + 1];
    u64 sv = *(const u64*)&zin[(size_t)sn * 64 + 4 * fq];
    float s0 = 0.f, s1 = 0.f, s2 = 0.f, s3 = 0.f;
    for (int e = rs; e < re; e += 16) {
      int c0 = lcol[e + q];
      int c1 = lcol[e + 4 + q];
      int c2 = lcol[e + 8 + q];
      int c3 = lcol[e + 12 + q];
      u64 v0 = *(const u64*)&zin[(size_t)c0 * 64 + 4 * fq];
      u64 v1 = *(const u64*)&zin[(size_t)c1 * 64 + 4 * fq];
      u64 v2 = *(const u64*)&zin[(size_t)c2 * 64 + 4 * fq];
      u64 v3 = *(const u64*)&zin[(size_t)c3 * 64 + 4 * fq];
      u32 l0 = (u32)v0, h0 = (u32)(v0 >> 32);
      u32 l1 = (u32)v1, h1 = (u32)(v1 >> 32);
      u32 l2 = (u32)v2, h2 = (u32)(v2 >> 32);
      u32 l3 = (u32)v3, h3 = (u32)(v3 >> 32);
      s0 += __uint_as_float(l0 << 16);
      s1 += __uint_as_float(l0 & 0xffff0000u);
      s2 += __uint_as_float(h0 << 16);
      s3 += __uint_as_float(h0 & 0xffff0000u);
      s0 += __uint_as_float(l1 << 16);
      s1 += __uint_as_float(l1 & 0xffff0000u);
      s2 += __uint_as_float(h1 << 16);
      s3 += __uint_as_float(h1 & 0xffff0000u);
      s0 += __uint_as_float(l2 << 16);
      s1 += __uint_as_float(l2 & 0xffff0000u);
      s2 += __uint_as_float(h2 << 16);
      s3 += __uint_as_float(h2 & 0xffff0000u);
      s0 += __uint_as_float(l3 << 16);
      s1 += __uint_as_float(l3 & 0xffff0000u);
      s2 += __uint_as_float(h3 << 16);
      s3 += __uint_as_float(h3 & 0xffff0000u);
    }
    // butterfly across the 4 row-quarters
    s0 += __shfl_xor(s0, 16);
    s1 += __shfl_xor(s1, 16);
    s2 += __shfl_xor(s2, 16);
    s3 += __shfl_xor(s3, 16);
    s0 += __shfl_xor(s0, 32);
    s1 += __shfl_xor(s1, 32);
    s2 += __shfl_xor(s2, 32);
    s3 += __shfl_xor(s3, 32);
    u32 sl = (u32)sv, sh = (u32)(sv >> 32);
    float h0v = fmaxf(s0 + e1 * __uint_as_float(sl << 16) + b1v4.x, 0.f);
    float h1v = fmaxf(s1 + e1 * __uint_as_float(sl & 0xffff0000u) + b1v4.y, 0.f);
    float h2v = fmaxf(s2 + e1 * __uint_as_float(sh << 16) + b1v4.z, 0.f);
    float h3v = fmaxf(s3 + e1 * __uint_as_float(sh & 0xffff0000u) + b1v4.w, 0.f);
    if (q == 0) {
      u32 p0 = (u32)f2b(h0v) | ((u32)f2b(h1v) << 16);
      u32 p1 = (u32)f2b(h2v) | ((u32)f2b(h3v) << 16);
      *(u32*)&H1[ln * HSTR + 4 * fq] = p0;
      *(u32*)&H1[ln * HSTR + 4 * fq + 2] = p1;
    }
  }
  __syncthreads();  // lcol reads done block-wide; H1 fully written

  const int mrow = lane & 15;
  const int quad = lane >> 4;
  if (wv < 4) {
    // matmul1: H2 = relu(H1 @ w2 + b2)  (A rows = 16-row quarter wv)
    f32x4 m1[4];
#pragma unroll
    for (int nt = 0; nt < 4; ++nt) {
      f32x4 acc = {0.f, 0.f, 0.f, 0.f};
#pragma unroll
      for (int ks = 0; ks < 2; ++ks) {
        short8 afr = *(const short8*)&H1[(wv * 16 + mrow) * HSTR + ks * 32 + quad * 8];
        short8 bfr = *(const short8*)&w2h[((nt * 2 + ks) * 64 + lane) * 8];
        acc = __builtin_amdgcn_mfma_f32_16x16x32_bf16(afr, bfr, acc, 0, 0, 0);
      }
      m1[nt] = acc;
    }
    LDS_FENCE();
#pragma unroll
    for (int nt = 0; nt < 4; ++nt) {
      float bb = b2s[nt * 16 + mrow];
#pragma unroll
      for (int r = 0; r < 4; ++r)
        H2[(wv * 16 + quad * 4 + r) * HSTR + nt * 16 + mrow] =
            f2b(fmaxf(m1[nt][r] + bb, 0.f));
    }
  }
  __syncthreads();  // H2 visible to all waves for pooling

  // fused pooling: wave wv owns rows wv*8..wv*8+7 of H2, lane = feature
  {
    const int n0p = wv * 8;
    float s = 0.f, m = 0.f;
    int cur = bt[n0p];
#pragma unroll 1
    for (int j = 0; j < 8; ++j) {
      int b = bt[n0p + j];
      if (b != cur) {
        if (cur >= 0) {
          atomicAdd(&gsum[cur * 192 + li * 64 + lane], s);
          atomicMax((u32*)&gmax[cur * 192 + li * 64 + lane], __float_as_uint(m));
        }
        s = 0.f;
        m = 0.f;
        cur = b;
      }
      if (b >= 0) {
        float v = b2f(H2[(n0p + j) * HSTR + lane]);
        s += v;
        m = fmaxf(m, v);
      }
    }
    if (cur >= 0) {
      atomicAdd(&gsum[cur * 192 + li * 64 + lane], s);
      atomicMax((u32*)&gmax[cur * 192 + li * 64 + lane], __float_as_uint(m));
    }
  }

  if (HAS_NEXT) {
    __syncthreads();  // pooling reads of H2 done; H1 fully dead
    for (int i = tid; i < 512; i += 512)
      ((int4*)w1nh)[i] = ((const int4*)w1nf)[i];
    __syncthreads();
    if (wv < 4) {
      // matmul2: zn = H2 @ w1n (A rows = own 16-row quarter)
      f32x4 m2[4];
#pragma unroll
      for (int nt = 0; nt < 4; ++nt) {
        f32x4 acc = {0.f, 0.f, 0.f, 0.f};
#pragma unroll
        for (int ks = 0; ks < 2; ++ks) {
          short8 afr = *(const short8*)&H2[(wv * 16 + mrow) * HSTR + ks * 32 + quad * 8];
          short8 bfr = *(const short8*)&w1nh[((nt * 2 + ks) * 64 + lane) * 8];
          acc = __builtin_amdgcn_mfma_f32_16x16x32_bf16(afr, bfr, acc, 0, 0, 0);
        }
        m2[nt] = acc;
      }
      LDS_FENCE();  // all A-reads of own H2 rows done before overwrite
#pragma unroll
      for (int nt = 0; nt < 4; ++nt)
#pragma unroll
        for (int r = 0; r < 4; ++r)
          H2[(wv * 16 + quad * 4 + r) * HSTR + nt * 16 + mrow] = f2b(m2[nt][r]);
    }
    __syncthreads();
    for (int i = tid; i < 2048; i += 512) {
      int n = i >> 5, kk = i & 31;
      int nn = base + n;
      if (nn < NNODES)
        *(u32*)&zn[(size_t)nn * 64 + 2 * kk] = *(u32*)&H2[n * HSTR + 2 * kk];
    }
  }
}

// ---------------- Head: pooled stats -> fc1 -> fc2 -> sigmoid -------------

__global__ __launch_bounds__(256) void head_kernel(
    const float* __restrict__ gsum, const float* __restrict__ gmax,
    const int* __restrict__ gcnt, const float* __restrict__ fc1w,
    const float* __restrict__ fc1b, const float* __restrict__ fc2w,
    const float* __restrict__ fc2b, float* __restrict__ out) {
  __shared__ float gs[4 * 576];
  int tid = threadIdx.x;
  int g0 = blockIdx.x * 4;
  for (int i = tid; i < 4 * 192; i += 256) {
    int w = i / 192, idx = i - w * 192;
    int gi = g0 + w;
    float S = gsum[gi * 192 + idx];
    float M = gmax[gi * 192 + idx];
    float C = (float)gcnt[gi];
    gs[w * 576 + idx] = S / fmaxf(C, 1.0f);
    gs[w * 576 + 192 + idx] = M;
    gs[w * 576 + 384 + idx] = S;
  }
  __syncthreads();
  int wv = tid >> 6, lane = tid & 63;
  int gi = g0 + wv;
  const float* grow = &gs[wv * 576];
  float acc = fc1b[lane];
#pragma unroll 8
  for (int k = 0; k < 576; ++k) acc += grow[k] * fc1w[k * 64 + lane];
  acc = fmaxf(acc, 0.f);
  float p0 = acc * fc2w[lane * 2 + 0];
  float p1 = acc * fc2w[lane * 2 + 1];
  for (int off = 32; off; off >>= 1) {
    p0 += __shfl_down(p0, off);
    p1 += __shfl_down(p1, off);
  }
  if (lane == 0) {
    out[gi * 2 + 0] = 1.f / (1.f + __expf(-(p0 + fc2b[0])));
    out[gi * 2 + 1] = 1.f / (1.f + __expf(-(p1 + fc2b[1])));
  }
}

// ---------------- launch ----------------

extern "C" void kernel_launch(void* const* d_in, const int* in_sizes, int n_in,
                              void* d_out, int out_size, void* d_ws,
                              size_t ws_size, hipStream_t stream) {
  const float* x = (const float*)d_in[0];
  const int* ei = (const int*)d_in[1];
  const int* src = ei;
  const int* dst = ei + NEDGES;
  const int* batch = (const int*)d_in[2];
  const float* lw1[3] = {(const float*)d_in[3], (const float*)d_in[7],
                         (const float*)d_in[11]};
  const float* lb1[3] = {(const float*)d_in[4], (const float*)d_in[8],
                         (const float*)d_in[12]};
  const float* lw2[3] = {(const float*)d_in[5], (const float*)d_in[9],
                         (const float*)d_in[13]};
  const float* lb2[3] = {(const float*)d_in[6], (const float*)d_in[10],
                         (const float*)d_in[14]};
  const float* eps = (const float*)d_in[15];
  const float* fc1w = (const float*)d_in[16];
  const float* fc1b = (const float*)d_in[17];
  const float* fc2w = (const float*)d_in[18];
  const float* fc2b = (const float*)d_in[19];
  float* out = (float*)d_out;

  char* p = (char*)d_ws;
  auto carve = [&](size_t bytes) {
    void* r = (void*)p;
    p += (bytes + 1023) & ~(size_t)1023;
    return r;
  };
  int* gcur = (int*)carve((NB + 4) * 4);
  int* st = (int*)carve((size_t)NB * BCAP * 4);
  int* glofs = (int*)carve((size_t)NBH * GOFS * 4);
  int* glcol = (int*)carve((size_t)NBH * LCAP * 4);
  u16* w1f = (u16*)carve(8192 * 2);
  u16* w2f0 = (u16*)carve(4096 * 2);
  u16* w2f1 = (u16*)carve(4096 * 2);
  u16* w2f2 = (u16*)carve(4096 * 2);
  u16* w1nf1 = (u16*)carve(4096 * 2);
  u16* w1nf2 = (u16*)carve(4096 * 2);
  u16* zA = (u16*)carve((size_t)(NNODES + 1) * 64 * 2);
  u16* zB = (u16*)carve((size_t)(NNODES + 1) * 64 * 2);
  float* gsum = (float*)carve((size_t)NGRAPHS * 192 * 4);
  float* gmax = (float*)carve((size_t)NGRAPHS * 192 * 4);
  int* gcnt = (int*)carve(NGRAPHS * 4);

  setup_kernel<<<8, 256, 0, stream>>>(gcur, zA, zB, batch, gcnt, lw1[0],
                                      lw2[0], lw2[1], lw2[2], lw1[1], lw1[2],
                                      w1f, w2f0, w2f1, w2f2, w1nf1, w1nf2);
  hipMemsetAsync(gsum, 0, (size_t)NGRAPHS * 192 * 4 * 2, stream);
  bin_kernel<<<NCHUNKS, 512, 0, stream>>>(src, dst, gcur, st);
  csr_kernel<<<NBH, 256, 0, stream>>>(gcur, st, glofs, glcol);

  gemm128_kernel<<<1563, 256, 0, stream>>>(x, w1f, zA);

  agg_kernel<true><<<NBH, 512, 0, stream>>>(zA, lb1[0], w2f0, lb2[0], w1nf1,
                                            eps, 0, glofs, glcol, batch, gsum,
                                            gmax, zB);
  agg_kernel<true><<<NBH, 512, 0, stream>>>(zB, lb1[1], w2f1, lb2[1], w1nf2,
                                            eps, 1, glofs, glcol, batch, gsum,
                                            gmax, zA);
  agg_kernel<false><<<NBH, 512, 0, stream>>>(zA, lb1[2], w2f2, lb2[2],
                                             (const u16*)nullptr, eps, 2, glofs,
                                             glcol, batch, gsum, gmax,
                                             (u16*)nullptr);

  head_kernel<<<NGRAPHS / 4, 256, 0, stream>>>(gsum, gmax, gcnt, fc1w, fc1b,
                                               fc2w, fc2b, out);
}